// Round 5
// baseline (189.474 us; speedup 1.0000x reference)
//
#include <hip/hip_runtime.h>

#define H 64
#define NPIX 65536
#define LBATCH 8
#define LC 24
#define NCH 8              // chunks per lc (192 blocks of 1024 threads)
#define PBT 8192           // pixels per block
#define SP 2048            // pixels staged per pass (4 passes)
#define EPSF 1e-6f
#define LN2_50 34.6573590f // 50 * ln(2): U50 = 50*(ln a - ln b) = LN2_50*(log2 a - log2 b)
#define NPART (LC * NCH)             // 192 partial histograms
#define PART_FLOATS (NPART * H * H)  // 3.1 MB of d_ws

typedef _Float16 h8 __attribute__((ext_vector_type(8)));   // MFMA operand view
typedef __fp16   g2 __attribute__((ext_vector_type(2)));   // cvt_pkrtz result view
typedef float f32x16 __attribute__((ext_vector_type(16)));
union H8u { h8 v8; g2 v2[4]; };                            // layout-identical pun

#define PK(a, b) __builtin_amdgcn_cvt_pkrtz((a), (b))

// 4 inverse-quadratic evals with ONE v_rcp_f32:
// 1/q_i = (prod of other three q) * rcp(q0*q1*q2*q3). q in [1, 7e5] so the
// product <= 2.4e23 stays normal-range fp32; extra rounding ~3e-7 relative.
#define KEV4(k0, k1, k2, k3, d0, d1, d2, d3) { \
    const float q0 = fmaf((d0), (d0), 1.0f); \
    const float q1 = fmaf((d1), (d1), 1.0f); \
    const float q2 = fmaf((d2), (d2), 1.0f); \
    const float q3 = fmaf((d3), (d3), 1.0f); \
    const float p01 = q0 * q1, p23 = q2 * q3; \
    const float r = __builtin_amdgcn_rcpf(p01 * p23); \
    const float r23 = p23 * r, r01 = p01 * r; \
    k0 = q1 * r23; k1 = q0 * r23; k2 = q3 * r01; k3 = q2 * r01; }

// One 1024-thread block per (lc, 8192-px chunk). Key change vs the ~104us
// version: stores to d_ws drain at only ~180 GB/s (measured across 5 rounds:
// dur ~= base + write_bytes/180GB/s, independent of store mechanism), so the
// 12.58 MB of per-block partials WAS the bottleneck. 16 waves now share one
// accumulator set -> 192 partials (3.1 MB) instead of 768 (12.6 MB).
// Staging runs in 4 passes of 2048 px through a 24 KB LDS buffer; per-wave
// K-work is identical to the proven config (32 K-steps of 16 px).
__global__ __launch_bounds__(1024, 4) void hist_main(const float* __restrict__ x,
                                                     float* __restrict__ ws) {
    __shared__ float sU[SP];
    __shared__ float sV[SP];
    __shared__ float sW[SP];
    __shared__ float sHist[H * H];

    const int tid  = threadIdx.x;
    const int wv   = tid >> 6;         // 0..15
    const int lane = tid & 63;
    const int hf   = lane >> 5;
    const int ln   = lane & 31;
    const int lc   = blockIdx.y;
    const int l    = lc / 3;
    const int c    = lc - 3 * l;

    *(float4*)&sHist[tid * 4] = make_float4(0.f, 0.f, 0.f, 0.f);

    const float* __restrict__ x0p = x + (l * 3 + 0) * NPIX;
    const float* __restrict__ x1p = x + (l * 3 + 1) * NPIX;
    const float* __restrict__ x2p = x + (l * 3 + 2) * NPIX;
    const int base = blockIdx.x * PBT;

    const float step50 = 50.0f * (6.0f / 63.0f);
    const float ou0 = -150.0f + step50 * (float)ln;  // u/v bins [0,32)
    const float ou1 = ou0 + step50 * 32.0f;          // u/v bins [32,64)

    f32x16 acc00, acc01, acc10, acc11;
    #pragma unroll
    for (int i = 0; i < 16; i++) { acc00[i] = 0.f; acc01[i] = 0.f; acc10[i] = 0.f; acc11[i] = 0.f; }

    const int wbase = wv * (SP / 16);  // 128-px slice per wave per pass

    for (int pass = 0; pass < PBT / SP; pass++) {
        // ---- prep 2048 px cooperatively (2 px/thread, float2 loads) ----
        {
            const int ploc = tid * 2;
            const int gp = base + pass * SP + ploc;
            const float2 r0 = *(const float2*)&x0p[gp];
            const float2 r1 = *(const float2*)&x1p[gp];
            const float2 r2 = *(const float2*)&x2p[gp];
            float2 U2, V2, W2;
            #define PREP(E) { \
                const float v0 = fminf(fmaxf(r0.E, 0.0f), 1.0f); \
                const float v1 = fminf(fmaxf(r1.E, 0.0f), 1.0f); \
                const float v2 = fminf(fmaxf(r2.E, 0.0f), 1.0f); \
                W2.E = __builtin_amdgcn_sqrtf(fmaf(v0, v0, fmaf(v1, v1, fmaf(v2, v2, EPSF)))); \
                const float lg0 = __builtin_amdgcn_logf(v0 + EPSF); \
                const float lg1 = __builtin_amdgcn_logf(v1 + EPSF); \
                const float lg2 = __builtin_amdgcn_logf(v2 + EPSF); \
                float U, V; \
                if (c == 0)      { U = lg0 - lg1; V = lg0 - lg2; } \
                else if (c == 1) { U = lg1 - lg0; V = lg1 - lg2; } \
                else             { U = lg2 - lg0; V = lg2 - lg1; } \
                U2.E = LN2_50 * U; V2.E = LN2_50 * V; }
            PREP(x) PREP(y)
            #undef PREP
            *(float2*)&sU[ploc] = U2;
            *(float2*)&sV[ploc] = V2;
            *(float2*)&sW[ploc] = W2;
        }
        __syncthreads();

        // ---- 8 MFMA K-steps over this wave's 128-px slice ----
        #pragma unroll 2
        for (int ks = 0; ks < SP / 16 / 16; ks++) {
            const int kb = wbase + ks * 16 + hf * 8;   // half-wave's 8 k-pixels
            const float4 ua = *(const float4*)&sU[kb];
            const float4 ub = *(const float4*)&sU[kb + 4];
            const float4 va = *(const float4*)&sV[kb];
            const float4 vb = *(const float4*)&sV[kb + 4];
            const float4 wa = *(const float4*)&sW[kb];
            const float4 wb = *(const float4*)&sW[kb + 4];
            H8u A0, A1, B0, B1;
            float k0, k1, k2, k3;
            KEV4(k0, k1, k2, k3, ua.x - ou0, ua.y - ou0, ua.z - ou0, ua.w - ou0)
            A0.v2[0] = PK(wa.x * k0, wa.y * k1);
            A0.v2[1] = PK(wa.z * k2, wa.w * k3);
            KEV4(k0, k1, k2, k3, ub.x - ou0, ub.y - ou0, ub.z - ou0, ub.w - ou0)
            A0.v2[2] = PK(wb.x * k0, wb.y * k1);
            A0.v2[3] = PK(wb.z * k2, wb.w * k3);
            KEV4(k0, k1, k2, k3, ua.x - ou1, ua.y - ou1, ua.z - ou1, ua.w - ou1)
            A1.v2[0] = PK(wa.x * k0, wa.y * k1);
            A1.v2[1] = PK(wa.z * k2, wa.w * k3);
            KEV4(k0, k1, k2, k3, ub.x - ou1, ub.y - ou1, ub.z - ou1, ub.w - ou1)
            A1.v2[2] = PK(wb.x * k0, wb.y * k1);
            A1.v2[3] = PK(wb.z * k2, wb.w * k3);
            KEV4(k0, k1, k2, k3, va.x - ou0, va.y - ou0, va.z - ou0, va.w - ou0)
            B0.v2[0] = PK(k0, k1);
            B0.v2[1] = PK(k2, k3);
            KEV4(k0, k1, k2, k3, vb.x - ou0, vb.y - ou0, vb.z - ou0, vb.w - ou0)
            B0.v2[2] = PK(k0, k1);
            B0.v2[3] = PK(k2, k3);
            KEV4(k0, k1, k2, k3, va.x - ou1, va.y - ou1, va.z - ou1, va.w - ou1)
            B1.v2[0] = PK(k0, k1);
            B1.v2[1] = PK(k2, k3);
            KEV4(k0, k1, k2, k3, vb.x - ou1, vb.y - ou1, vb.z - ou1, vb.w - ou1)
            B1.v2[2] = PK(k0, k1);
            B1.v2[3] = PK(k2, k3);
            acc00 = __builtin_amdgcn_mfma_f32_32x32x16_f16(A0.v8, B0.v8, acc00, 0, 0, 0);
            acc01 = __builtin_amdgcn_mfma_f32_32x32x16_f16(A0.v8, B1.v8, acc01, 0, 0, 0);
            acc10 = __builtin_amdgcn_mfma_f32_32x32x16_f16(A1.v8, B0.v8, acc10, 0, 0, 0);
            acc11 = __builtin_amdgcn_mfma_f32_32x32x16_f16(A1.v8, B1.v8, acc11, 0, 0, 0);
        }
        __syncthreads();   // staging is reused next pass
    }

    // merge 16 wave accumulators (C/D layout: col=ln, row=(r&3)+8*(r>>2)+4*hf)
    #pragma unroll
    for (int r = 0; r < 16; r++) {
        const int row = (r & 3) + 8 * (r >> 2) + 4 * hf;
        atomicAdd(&sHist[row * 64 + ln],             acc00[r]);
        atomicAdd(&sHist[row * 64 + 32 + ln],        acc01[r]);
        atomicAdd(&sHist[(row + 32) * 64 + ln],      acc10[r]);
        atomicAdd(&sHist[(row + 32) * 64 + 32 + ln], acc11[r]);
    }
    __syncthreads();

    // flush partial histogram to private ws slice (1 float4/thread)
    float* __restrict__ g = ws + (lc * NCH + blockIdx.x) * (H * H);
    *(float4*)&g[tid * 4] = *(const float4*)&sHist[tid * 4];
}

// 96 blocks: one per (lc, quarter). Sum 8 chunk-partials, write out,
// emit per-block mass partial to wsq (plain store — no atomics, no zeroing).
__global__ __launch_bounds__(256) void hist_reduce(const float* __restrict__ ws,
                                                   float* __restrict__ out,
                                                   float* __restrict__ wsq) {
    const int lc  = blockIdx.x >> 2;
    const int off = (blockIdx.x & 3) * 1024 + threadIdx.x * 4;
    float4 a = make_float4(0.f, 0.f, 0.f, 0.f);
    #pragma unroll
    for (int ch = 0; ch < NCH; ch++) {
        const float4 v = *(const float4*)&ws[(lc * NCH + ch) * (H * H) + off];
        a.x += v.x; a.y += v.y; a.z += v.z; a.w += v.w;
    }
    *(float4*)&out[lc * (H * H) + off] = a;

    float s = (a.x + a.y) + (a.z + a.w);
    #pragma unroll
    for (int o = 32; o > 0; o >>= 1) s += __shfl_down(s, o, 64);
    __shared__ float ps[4];
    if ((threadIdx.x & 63) == 0) ps[threadIdx.x >> 6] = s;
    __syncthreads();
    if (threadIdx.x == 0) wsq[blockIdx.x] = (ps[0] + ps[1]) + (ps[2] + ps[3]);
}

// 96 blocks: normalize. Total for sample l = sum of its 12 wsq partials.
__global__ __launch_bounds__(256) void hist_scale(float* __restrict__ out,
                                                  const float* __restrict__ wsq) {
    const int lc = blockIdx.x >> 2;
    const int l  = lc / 3;
    float T = 0.f;
    #pragma unroll
    for (int j = 0; j < 12; j++) T += wsq[l * 12 + j];
    const float inv = 1.0f / (T + EPSF);
    const int off = (blockIdx.x & 3) * 1024 + threadIdx.x * 4;
    float4 v = *(const float4*)&out[lc * (H * H) + off];
    v.x *= inv; v.y *= inv; v.z *= inv; v.w *= inv;
    *(float4*)&out[lc * (H * H) + off] = v;
}

extern "C" void kernel_launch(void* const* d_in, const int* in_sizes, int n_in,
                              void* d_out, int out_size, void* d_ws, size_t ws_size,
                              hipStream_t stream) {
    const float* x = (const float*)d_in[0];
    float* out = (float*)d_out;
    float* ws = (float*)d_ws;   // needs 3.1 MB + 384 B

    hipLaunchKernelGGL(hist_main,   dim3(NCH, LC), dim3(1024), 0, stream, x, ws);
    hipLaunchKernelGGL(hist_reduce, dim3(96),      dim3(256),  0, stream, ws, out, ws + PART_FLOATS);
    hipLaunchKernelGGL(hist_scale,  dim3(96),      dim3(256),  0, stream, out, ws + PART_FLOATS);
}

// Round 6
// 172.914 us; speedup vs baseline: 1.0958x; 1.0958x over previous
//
#include <hip/hip_runtime.h>

#define H 64
#define NPIX 65536
#define LBATCH 8
#define LC 24
#define S_CHUNKS 32
#define PB 2048            // pixels per block
#define SLICE 6144         // floats per block ws slice: [U 2048][V 2048][W 2048]
#define EPSF 1e-6f
#define LN2_50 34.6573590f // 50 * ln(2): U50 = 50*(ln a - ln b) = LN2_50*(log2 a - log2 b)
#define NPART (LC * S_CHUNKS)        // 768 slices
#define WS_FLOATS (NPART * SLICE)    // 18.87 MB of d_ws (proven >=25.2 MB available)

typedef _Float16 h8 __attribute__((ext_vector_type(8)));   // MFMA operand view
typedef __fp16   g2 __attribute__((ext_vector_type(2)));   // cvt_pkrtz result view
typedef float f32x16 __attribute__((ext_vector_type(16)));
union H8u { h8 v8; g2 v2[4]; };                            // layout-identical pun

#define PK(a, b) __builtin_amdgcn_cvt_pkrtz((a), (b))

// 4 inverse-quadratic evals with ONE v_rcp_f32:
// 1/q_i = (prod of other three q) * rcp(q0*q1*q2*q3). q in [1, 7e5] so the
// product <= 2.4e23 stays normal-range fp32; extra rounding ~3e-7 relative.
#define KEV4(k0, k1, k2, k3, d0, d1, d2, d3) { \
    const float q0 = fmaf((d0), (d0), 1.0f); \
    const float q1 = fmaf((d1), (d1), 1.0f); \
    const float q2 = fmaf((d2), (d2), 1.0f); \
    const float q3 = fmaf((d3), (d3), 1.0f); \
    const float p01 = q0 * q1, p23 = q2 * q3; \
    const float r = __builtin_amdgcn_rcpf(p01 * p23); \
    const float r23 = p23 * r, r01 = p01 * r; \
    k0 = q1 * r23; k1 = q0 * r23; k2 = q3 * r01; k3 = q2 * r01; }

// One block per (lc, 2048-px chunk). THEORY UNDER TEST: all six prior rounds
// are capped at ~28% per-CU VALU issue by the LDS pipe serving wave-uniform
// ds_read_b128 broadcasts (uniform addr touches only 4 banks -> ~64cy each,
// invisible to SQ_LDS_BANK_CONFLICT). This version stages U/V/W in a private
// GLOBAL slice of d_ws and reads it back with wave-uniform global_load_dwordx4
// (single L1 line lookup + broadcast, vmcnt-pipelined). LDS keeps only sHist.
// The 16KB partial histogram flushes into the block's own dead staging slice.
__global__ __launch_bounds__(256, 3) void hist_main(const float* __restrict__ x,
                                                    float* __restrict__ ws) {
    __shared__ float sHist[H * H];

    const int tid  = threadIdx.x;
    const int wv   = tid >> 6;
    const int lane = tid & 63;
    const int hf   = lane >> 5;
    const int ln   = lane & 31;
    const int lc   = blockIdx.y;
    const int l    = lc / 3;
    const int c    = lc - 3 * l;

    #pragma unroll
    for (int r = 0; r < 4; r++)
        *(float4*)&sHist[(r * 256 + tid) * 4] = make_float4(0.f, 0.f, 0.f, 0.f);

    const float* __restrict__ x0p = x + (l * 3 + 0) * NPIX;
    const float* __restrict__ x1p = x + (l * 3 + 1) * NPIX;
    const float* __restrict__ x2p = x + (l * 3 + 2) * NPIX;
    const int base = blockIdx.x * PB;

    float* __restrict__ stg = ws + (size_t)(lc * S_CHUNKS + blockIdx.x) * SLICE;
    float* __restrict__ sU = stg;
    float* __restrict__ sV = stg + PB;
    float* __restrict__ sW = stg + 2 * PB;

    // ---- Phase 1: cooperative pixel prep into GLOBAL staging (L2-resident) ----
    #pragma unroll
    for (int pass = 0; pass < 2; pass++) {
        const int ploc = pass * 1024 + tid * 4;
        const float4 r0 = *(const float4*)&x0p[base + ploc];
        const float4 r1 = *(const float4*)&x1p[base + ploc];
        const float4 r2 = *(const float4*)&x2p[base + ploc];
        float4 U4, V4, W4;
        #define PREP(E) { \
            const float v0 = fminf(fmaxf(r0.E, 0.0f), 1.0f); \
            const float v1 = fminf(fmaxf(r1.E, 0.0f), 1.0f); \
            const float v2 = fminf(fmaxf(r2.E, 0.0f), 1.0f); \
            W4.E = __builtin_amdgcn_sqrtf(fmaf(v0, v0, fmaf(v1, v1, fmaf(v2, v2, EPSF)))); \
            const float lg0 = __builtin_amdgcn_logf(v0 + EPSF); \
            const float lg1 = __builtin_amdgcn_logf(v1 + EPSF); \
            const float lg2 = __builtin_amdgcn_logf(v2 + EPSF); \
            float U, V; \
            if (c == 0)      { U = lg0 - lg1; V = lg0 - lg2; } \
            else if (c == 1) { U = lg1 - lg0; V = lg1 - lg2; } \
            else             { U = lg2 - lg0; V = lg2 - lg1; } \
            U4.E = LN2_50 * U; V4.E = LN2_50 * V; }
        PREP(x) PREP(y) PREP(z) PREP(w)
        #undef PREP
        *(float4*)&sU[ploc] = U4;
        *(float4*)&sV[ploc] = V4;
        *(float4*)&sW[ploc] = W4;
    }
    __syncthreads();   // waits vmcnt(0) per wave: staging visible via L2

    // ---- Phase 2: MFMA K-loop; uniform global_load_dwordx4 broadcasts ----
    const float step50 = 50.0f * (6.0f / 63.0f);
    const float ou0 = -150.0f + step50 * (float)ln;  // u/v bins [0,32)
    const float ou1 = ou0 + step50 * 32.0f;          // u/v bins [32,64)

    f32x16 acc00, acc01, acc10, acc11;
    #pragma unroll
    for (int i = 0; i < 16; i++) { acc00[i] = 0.f; acc01[i] = 0.f; acc10[i] = 0.f; acc11[i] = 0.f; }

    const int wbase = wv * 512;
    #pragma unroll 2
    for (int ks = 0; ks < 32; ks++) {
        const int kb = wbase + ks * 16 + hf * 8;     // half-wave's 8 k-pixels
        const float4 ua = *(const float4*)&sU[kb];
        const float4 ub = *(const float4*)&sU[kb + 4];
        const float4 va = *(const float4*)&sV[kb];
        const float4 vb = *(const float4*)&sV[kb + 4];
        const float4 wa = *(const float4*)&sW[kb];
        const float4 wb = *(const float4*)&sW[kb + 4];
        H8u A0, A1, B0, B1;
        float k0, k1, k2, k3;
        KEV4(k0, k1, k2, k3, ua.x - ou0, ua.y - ou0, ua.z - ou0, ua.w - ou0)
        A0.v2[0] = PK(wa.x * k0, wa.y * k1);
        A0.v2[1] = PK(wa.z * k2, wa.w * k3);
        KEV4(k0, k1, k2, k3, ub.x - ou0, ub.y - ou0, ub.z - ou0, ub.w - ou0)
        A0.v2[2] = PK(wb.x * k0, wb.y * k1);
        A0.v2[3] = PK(wb.z * k2, wb.w * k3);
        KEV4(k0, k1, k2, k3, ua.x - ou1, ua.y - ou1, ua.z - ou1, ua.w - ou1)
        A1.v2[0] = PK(wa.x * k0, wa.y * k1);
        A1.v2[1] = PK(wa.z * k2, wa.w * k3);
        KEV4(k0, k1, k2, k3, ub.x - ou1, ub.y - ou1, ub.z - ou1, ub.w - ou1)
        A1.v2[2] = PK(wb.x * k0, wb.y * k1);
        A1.v2[3] = PK(wb.z * k2, wb.w * k3);
        KEV4(k0, k1, k2, k3, va.x - ou0, va.y - ou0, va.z - ou0, va.w - ou0)
        B0.v2[0] = PK(k0, k1);
        B0.v2[1] = PK(k2, k3);
        KEV4(k0, k1, k2, k3, vb.x - ou0, vb.y - ou0, vb.z - ou0, vb.w - ou0)
        B0.v2[2] = PK(k0, k1);
        B0.v2[3] = PK(k2, k3);
        KEV4(k0, k1, k2, k3, va.x - ou1, va.y - ou1, va.z - ou1, va.w - ou1)
        B1.v2[0] = PK(k0, k1);
        B1.v2[1] = PK(k2, k3);
        KEV4(k0, k1, k2, k3, vb.x - ou1, vb.y - ou1, vb.z - ou1, vb.w - ou1)
        B1.v2[2] = PK(k0, k1);
        B1.v2[3] = PK(k2, k3);
        acc00 = __builtin_amdgcn_mfma_f32_32x32x16_f16(A0.v8, B0.v8, acc00, 0, 0, 0);
        acc01 = __builtin_amdgcn_mfma_f32_32x32x16_f16(A0.v8, B1.v8, acc01, 0, 0, 0);
        acc10 = __builtin_amdgcn_mfma_f32_32x32x16_f16(A1.v8, B0.v8, acc10, 0, 0, 0);
        acc11 = __builtin_amdgcn_mfma_f32_32x32x16_f16(A1.v8, B1.v8, acc11, 0, 0, 0);
    }

    // merge 4 wave accumulators (C/D layout: col=ln, row=(r&3)+8*(r>>2)+4*hf)
    #pragma unroll
    for (int r = 0; r < 16; r++) {
        const int row = (r & 3) + 8 * (r >> 2) + 4 * hf;
        atomicAdd(&sHist[row * 64 + ln],             acc00[r]);
        atomicAdd(&sHist[row * 64 + 32 + ln],        acc01[r]);
        atomicAdd(&sHist[(row + 32) * 64 + ln],      acc10[r]);
        atomicAdd(&sHist[(row + 32) * 64 + 32 + ln], acc11[r]);
    }
    __syncthreads();

    // flush partial histogram over the block's own (now dead) staging slice
    #pragma unroll
    for (int r = 0; r < 4; r++) {
        const int i = (r * 256 + tid) * 4;
        *(float4*)&stg[i] = *(const float4*)&sHist[i];
    }
}

// 96 blocks: one per (lc, quarter). Sum 32 chunk-partials (each at the head of
// its 6144-float slice), write out, emit per-block mass partial to wsq.
__global__ __launch_bounds__(256) void hist_reduce(const float* __restrict__ ws,
                                                   float* __restrict__ out,
                                                   float* __restrict__ wsq) {
    const int lc  = blockIdx.x >> 2;
    const int off = (blockIdx.x & 3) * 1024 + threadIdx.x * 4;
    float4 a = make_float4(0.f, 0.f, 0.f, 0.f);
    #pragma unroll 8
    for (int ch = 0; ch < S_CHUNKS; ch++) {
        const float4 v = *(const float4*)&ws[(size_t)(lc * S_CHUNKS + ch) * SLICE + off];
        a.x += v.x; a.y += v.y; a.z += v.z; a.w += v.w;
    }
    *(float4*)&out[lc * (H * H) + off] = a;

    float s = (a.x + a.y) + (a.z + a.w);
    #pragma unroll
    for (int o = 32; o > 0; o >>= 1) s += __shfl_down(s, o, 64);
    __shared__ float ps[4];
    if ((threadIdx.x & 63) == 0) ps[threadIdx.x >> 6] = s;
    __syncthreads();
    if (threadIdx.x == 0) wsq[blockIdx.x] = (ps[0] + ps[1]) + (ps[2] + ps[3]);
}

// 96 blocks: normalize. Total for sample l = sum of its 12 wsq partials.
__global__ __launch_bounds__(256) void hist_scale(float* __restrict__ out,
                                                  const float* __restrict__ wsq) {
    const int lc = blockIdx.x >> 2;
    const int l  = lc / 3;
    float T = 0.f;
    #pragma unroll
    for (int j = 0; j < 12; j++) T += wsq[l * 12 + j];
    const float inv = 1.0f / (T + EPSF);
    const int off = (blockIdx.x & 3) * 1024 + threadIdx.x * 4;
    float4 v = *(const float4*)&out[lc * (H * H) + off];
    v.x *= inv; v.y *= inv; v.z *= inv; v.w *= inv;
    *(float4*)&out[lc * (H * H) + off] = v;
}

extern "C" void kernel_launch(void* const* d_in, const int* in_sizes, int n_in,
                              void* d_out, int out_size, void* d_ws, size_t ws_size,
                              hipStream_t stream) {
    const float* x = (const float*)d_in[0];
    float* out = (float*)d_out;
    float* ws = (float*)d_ws;   // needs 18.87 MB + 384 B (>=25.2 MB proven in R3)

    hipLaunchKernelGGL(hist_main,   dim3(S_CHUNKS, LC), dim3(256), 0, stream, x, ws);
    hipLaunchKernelGGL(hist_reduce, dim3(96),           dim3(256), 0, stream, ws, out, ws + WS_FLOATS);
    hipLaunchKernelGGL(hist_scale,  dim3(96),           dim3(256), 0, stream, out, ws + WS_FLOATS);
}